// Round 7
// baseline (59.890 us; speedup 1.0000x reference)
//
#include <hip/hip_runtime.h>
#include <math.h>

// KDE via bf16 hi/lo split folded into K of mfma_f32_16x16x32_bf16.
//   arg = k2l*(dot(e,b) - 0.5|e|^2 - 0.5|b|^2),  k2l = exp(-2 log_bw)*log2(e)
//   eval data prescaled by k2l. Per 16x16 tile:
//     MFMA1: A=[Ah|Al] x B=[Bh|Bh]  -> Ah.Bh + Al.Bh
//     MFMA2: A=[Ah|An] x B=[Bl|Bn]  -> Ah.Bl + (cb+ce norm constants)
//   out += exp2(C).  Norms 3-way bf16 split (residual ~2^-27).
// Base packed per 16-row tile: plane1=[hi|lo], plane2=[hi|norm] (2KB/tile,
// one vaddr + imm offset). 2 C-tiles/wave, ~50 VGPR -> 8 waves/SIMD.

#define LOG_2PI_F 1.8378770664093453f
#define LOG2E_F   1.4426950408889634f

#define M_PTS 8192
#define N_PTS 16384
#define NCH   64                       // N chunks
#define ROWS_PER_CHUNK (N_PTS / NCH)   // 256
#define TPC (ROWS_PER_CHUNK / 16)      // 16 tiles of 16 base rows
#define TILE_USH 1024                  // 2 planes x 16 rows x 32 bf16
#define CHUNK_USH (TPC * TILE_USH)

typedef __attribute__((ext_vector_type(8))) short bf16x8;
typedef __attribute__((ext_vector_type(4))) float f32x4;

static __device__ __forceinline__ unsigned short f2bf(float x) {
    unsigned u = __float_as_uint(x);
    u += 0x7fffu + ((u >> 16) & 1u);          // RNE
    return (unsigned short)(u >> 16);
}
static __device__ __forceinline__ float bf2f(unsigned short h) {
    return __uint_as_float(((unsigned)h) << 16);
}
static __device__ __forceinline__ uint4 pack8(const unsigned short* a) {
    uint4 u;
    u.x = (unsigned)a[0] | ((unsigned)a[1] << 16);
    u.y = (unsigned)a[2] | ((unsigned)a[3] << 16);
    u.z = (unsigned)a[4] | ((unsigned)a[5] << 16);
    u.w = (unsigned)a[6] | ((unsigned)a[7] << 16);
    return u;
}

// ---------------------------------------------------------------------------
// pack: base rows -> tiled [hi|lo],[hi|norm] planes; eval rows -> planar h/l/n.
__global__ __launch_bounds__(256) void kde_pack(
        const float* __restrict__ xe, const float* __restrict__ xb,
        const float* __restrict__ log_bw,
        unsigned short* __restrict__ bint,
        unsigned short* __restrict__ eh, unsigned short* __restrict__ el,
        unsigned short* __restrict__ en) {
    int r = blockIdx.x * 256 + threadIdx.x;
    if (r >= N_PTS + M_PTS) return;
    const float k2l = __expf(-2.f * log_bw[0]) * LOG2E_F;

    int is_eval = (r >= N_PTS);
    int rr = is_eval ? (r - N_PTS) : r;
    const float* src = is_eval ? xe : xb;
    float dscale = is_eval ? k2l : 1.0f;       // eval data prescaled

    const float4* row = (const float4*)(src + (size_t)rr * 16);
    unsigned short hs[16], ls[16], ns[16];
    float s = 0.f;
#pragma unroll
    for (int k = 0; k < 4; ++k) {
        float4 v = row[k];
        float c[4] = {v.x, v.y, v.z, v.w};
#pragma unroll
        for (int j = 0; j < 4; ++j) {
            s = fmaf(c[j], c[j], s);
            float d = c[j] * dscale;
            unsigned short h = f2bf(d);
            hs[k*4+j] = h;
            ls[k*4+j] = f2bf(d - bf2f(h));
        }
    }
    // 3-way bf16 split of the scaled norm constant
    float cn = -0.5f * s * k2l;
    unsigned short c0 = f2bf(cn);
    float r1 = cn - bf2f(c0);
    unsigned short c1 = f2bf(r1);
    unsigned short c2 = f2bf(r1 - bf2f(c1));
#pragma unroll
    for (int i = 0; i < 16; ++i) ns[i] = 0;
    if (is_eval) {
        ns[0] = 0x3F80; ns[1] = 0x3F80; ns[2] = 0x3F80;
        ns[3] = c0;     ns[4] = c1;     ns[5] = c2;
    } else {
        ns[0] = c0;     ns[1] = c1;     ns[2] = c2;
        ns[3] = 0x3F80; ns[4] = 0x3F80; ns[5] = 0x3F80;
    }

    if (is_eval) {
        uint4* dh = (uint4*)(eh + (size_t)rr * 16);
        uint4* dl = (uint4*)(el + (size_t)rr * 16);
        uint4* dn = (uint4*)(en + (size_t)rr * 16);
        dh[0] = pack8(hs); dh[1] = pack8(hs + 8);
        dl[0] = pack8(ls); dl[1] = pack8(ls + 8);
        dn[0] = pack8(ns); dn[1] = pack8(ns + 8);
    } else {
        int t = rr >> 4, q = rr & 15;
        unsigned short* p1 = bint + (size_t)t * TILE_USH + q * 32;  // [hi|lo]
        unsigned short* p2 = p1 + 512;                              // [hi|ns]
        uint4* d1 = (uint4*)p1;
        d1[0] = pack8(hs); d1[1] = pack8(hs + 8);
        d1[2] = pack8(ls); d1[3] = pack8(ls + 8);
        uint4* d2 = (uint4*)p2;
        d2[0] = pack8(hs); d2[1] = pack8(hs + 8);
        d2[2] = pack8(ns); d2[3] = pack8(ns + 8);
    }
}

// ---------------------------------------------------------------------------
// main: wave owns TWO 16x16 C tiles (32 eval cols) x one chunk (256 base rows).
// 4 waves/block share the chunk -> L1 reuse of A tiles. Target VGPR <= 64.
__global__ __launch_bounds__(256, 8) void kde_mfma(
        const unsigned short* __restrict__ eh, const unsigned short* __restrict__ el,
        const unsigned short* __restrict__ en,
        const unsigned short* __restrict__ bint,
        float* __restrict__ part) {
    const int lane = threadIdx.x & 63;
    const int widx = threadIdx.x >> 6;
    const int b = blockIdx.x;                 // 0..4095
    const int chunk = b >> 6;                 // 0..63 (block-uniform)
    const int etp = (b & 63) * 4 + widx;      // 0..255 -> 32 eval cols
    const int cl = lane & 15;
    const int kg = lane >> 4;                 // 0..3 (k-slice)

    // B fragments (eval), resident for whole kernel.
    // B1 = [Bh|Bh] (kg2,3 re-read hi); B2 = [Bl|Bn] (kg<2 from el, else en).
    const size_t c0i = ((size_t)etp * 32 + cl) * 16;
    const size_t c1i = c0i + 16 * 16;
    const int kgo = (kg & 1) * 8;
    const bf16x8 B1_0 = *(const bf16x8*)(eh + c0i + kgo);
    const bf16x8 B1_1 = *(const bf16x8*)(eh + c1i + kgo);
    const unsigned short* b2src = (kg < 2) ? el : en;
    const bf16x8 B2_0 = *(const bf16x8*)(b2src + c0i + kgo);
    const bf16x8 B2_1 = *(const bf16x8*)(b2src + c1i + kgo);

    // A: one vaddr; plane1 at +0, plane2 at +512 ushorts (imm offset)
    const unsigned short* pa =
        bint + (size_t)chunk * CHUNK_USH + (size_t)cl * 32 + (size_t)kg * 8;

    float acc0 = 0.f, acc1 = 0.f;
    const f32x4 Z = {0.f, 0.f, 0.f, 0.f};

#pragma unroll 1
    for (int t = 0; t < TPC; ++t) {
        const bf16x8 A1 = *(const bf16x8*)(pa);
        const bf16x8 A2 = *(const bf16x8*)(pa + 512);
        pa += TILE_USH;

        f32x4 C0 = __builtin_amdgcn_mfma_f32_16x16x32_bf16(A1, B1_0, Z, 0, 0, 0);
        C0 = __builtin_amdgcn_mfma_f32_16x16x32_bf16(A2, B2_0, C0, 0, 0, 0);
        f32x4 C1 = __builtin_amdgcn_mfma_f32_16x16x32_bf16(A1, B1_1, Z, 0, 0, 0);
        C1 = __builtin_amdgcn_mfma_f32_16x16x32_bf16(A2, B2_1, C1, 0, 0, 0);

        acc0 += __builtin_amdgcn_exp2f(C0[0]);
        acc0 += __builtin_amdgcn_exp2f(C0[1]);
        acc0 += __builtin_amdgcn_exp2f(C0[2]);
        acc0 += __builtin_amdgcn_exp2f(C0[3]);
        acc1 += __builtin_amdgcn_exp2f(C1[0]);
        acc1 += __builtin_amdgcn_exp2f(C1[1]);
        acc1 += __builtin_amdgcn_exp2f(C1[2]);
        acc1 += __builtin_amdgcn_exp2f(C1[3]);
    }

    // sum over the 4 kg row-groups (base rows) -> per-col partial
    acc0 += __shfl_xor(acc0, 16, 64);
    acc0 += __shfl_xor(acc0, 32, 64);
    acc1 += __shfl_xor(acc1, 16, 64);
    acc1 += __shfl_xor(acc1, 32, 64);
    if (lane < 16) {
        float* p = part + (size_t)chunk * M_PTS + (size_t)etp * 32;
        p[cl]      = acc0;
        p[16 + cl] = acc1;
    }
}

// ---------------------------------------------------------------------------
__global__ __launch_bounds__(256) void kde_reduce(
        const float* __restrict__ part, const float* __restrict__ log_bw,
        float* __restrict__ out) {
    int m = blockIdx.x * 256 + threadIdx.x;
    if (m >= M_PTS) return;
    float lb = log_bw[0];
    float scale = __expf(-8.f * LOG_2PI_F - lb) / (float)N_PTS;
    float s = 0.f;
#pragma unroll
    for (int c = 0; c < NCH; ++c) s += part[(size_t)c * M_PTS + m];
    out[m] = scale * s;
}

// ---------------------------------------------------------------------------
extern "C" void kernel_launch(void* const* d_in, const int* in_sizes, int n_in,
                              void* d_out, int out_size, void* d_ws, size_t ws_size,
                              hipStream_t stream) {
    const float* xe = (const float*)d_in[0];   // [8192,16]
    const float* xb = (const float*)d_in[1];   // [16384,16]
    const float* lb = (const float*)d_in[2];   // [1]
    float* out = (float*)d_out;                // [8192]

    unsigned short* bint = (unsigned short*)d_ws;            // 1024 tiles * 1024 ush
    unsigned short* eh = bint + (size_t)(N_PTS / 16) * TILE_USH;
    unsigned short* el = eh + (size_t)M_PTS * 16;
    unsigned short* en = el + (size_t)M_PTS * 16;
    float* part = (float*)(en + (size_t)M_PTS * 16);         // NCH*M_PTS floats

    kde_pack<<<(N_PTS + M_PTS) / 256, 256, 0, stream>>>(xe, xb, lb,
                                                        bint, eh, el, en);
    kde_mfma<<<4096, 256, 0, stream>>>(eh, el, en, bint, part);
    kde_reduce<<<M_PTS / 256, 256, 0, stream>>>(part, lb, out);
}

// Round 8
// 59.791 us; speedup vs baseline: 1.0016x; 1.0016x over previous
//
#include <hip/hip_runtime.h>
#include <math.h>

// KDE via bf16 hi/lo split folded into K of mfma_f32_16x16x32_bf16.
//   arg = k2l*(dot(e,b) - 0.5|e|^2 - 0.5|b|^2),  k2l = exp(-2 log_bw)*log2(e)
//   eval data prescaled by k2l. Per 16x16 tile:
//     MFMA1: A=[Ah|Al] x B=[Bh|Bh]  -> Ah.Bh + Al.Bh
//     MFMA2: A=[Ah|An] x B=[Bl|Bn]  -> Ah.Bl + (cb+ce norm constants)
//   out += exp2(C).  Norms 3-way bf16 split (residual ~2^-27).
// Round-8 change: register double-buffered A prefetch (loads for t+1 issued
// before computing t) -> dependent-load latency hidden; 4 acc chains; peeled
// last iteration. Target VGPR <= 64 -> 8 waves/SIMD.

#define LOG_2PI_F 1.8378770664093453f
#define LOG2E_F   1.4426950408889634f

#define M_PTS 8192
#define N_PTS 16384
#define NCH   64                       // N chunks
#define ROWS_PER_CHUNK (N_PTS / NCH)   // 256
#define TPC (ROWS_PER_CHUNK / 16)      // 16 tiles of 16 base rows
#define TILE_USH 1024                  // 2 planes x 16 rows x 32 bf16
#define CHUNK_USH (TPC * TILE_USH)

typedef __attribute__((ext_vector_type(8))) short bf16x8;
typedef __attribute__((ext_vector_type(4))) float f32x4;

static __device__ __forceinline__ unsigned short f2bf(float x) {
    unsigned u = __float_as_uint(x);
    u += 0x7fffu + ((u >> 16) & 1u);          // RNE
    return (unsigned short)(u >> 16);
}
static __device__ __forceinline__ float bf2f(unsigned short h) {
    return __uint_as_float(((unsigned)h) << 16);
}
static __device__ __forceinline__ uint4 pack8(const unsigned short* a) {
    uint4 u;
    u.x = (unsigned)a[0] | ((unsigned)a[1] << 16);
    u.y = (unsigned)a[2] | ((unsigned)a[3] << 16);
    u.z = (unsigned)a[4] | ((unsigned)a[5] << 16);
    u.w = (unsigned)a[6] | ((unsigned)a[7] << 16);
    return u;
}

// ---------------------------------------------------------------------------
// pack: base rows -> tiled [hi|lo],[hi|norm] planes; eval rows -> planar h/l/n.
__global__ __launch_bounds__(256) void kde_pack(
        const float* __restrict__ xe, const float* __restrict__ xb,
        const float* __restrict__ log_bw,
        unsigned short* __restrict__ bint,
        unsigned short* __restrict__ eh, unsigned short* __restrict__ el,
        unsigned short* __restrict__ en) {
    int r = blockIdx.x * 256 + threadIdx.x;
    if (r >= N_PTS + M_PTS) return;
    const float k2l = __expf(-2.f * log_bw[0]) * LOG2E_F;

    int is_eval = (r >= N_PTS);
    int rr = is_eval ? (r - N_PTS) : r;
    const float* src = is_eval ? xe : xb;
    float dscale = is_eval ? k2l : 1.0f;       // eval data prescaled

    const float4* row = (const float4*)(src + (size_t)rr * 16);
    unsigned short hs[16], ls[16], ns[16];
    float s = 0.f;
#pragma unroll
    for (int k = 0; k < 4; ++k) {
        float4 v = row[k];
        float c[4] = {v.x, v.y, v.z, v.w};
#pragma unroll
        for (int j = 0; j < 4; ++j) {
            s = fmaf(c[j], c[j], s);
            float d = c[j] * dscale;
            unsigned short h = f2bf(d);
            hs[k*4+j] = h;
            ls[k*4+j] = f2bf(d - bf2f(h));
        }
    }
    // 3-way bf16 split of the scaled norm constant
    float cn = -0.5f * s * k2l;
    unsigned short c0 = f2bf(cn);
    float r1 = cn - bf2f(c0);
    unsigned short c1 = f2bf(r1);
    unsigned short c2 = f2bf(r1 - bf2f(c1));
#pragma unroll
    for (int i = 0; i < 16; ++i) ns[i] = 0;
    if (is_eval) {
        ns[0] = 0x3F80; ns[1] = 0x3F80; ns[2] = 0x3F80;
        ns[3] = c0;     ns[4] = c1;     ns[5] = c2;
    } else {
        ns[0] = c0;     ns[1] = c1;     ns[2] = c2;
        ns[3] = 0x3F80; ns[4] = 0x3F80; ns[5] = 0x3F80;
    }

    if (is_eval) {
        uint4* dh = (uint4*)(eh + (size_t)rr * 16);
        uint4* dl = (uint4*)(el + (size_t)rr * 16);
        uint4* dn = (uint4*)(en + (size_t)rr * 16);
        dh[0] = pack8(hs); dh[1] = pack8(hs + 8);
        dl[0] = pack8(ls); dl[1] = pack8(ls + 8);
        dn[0] = pack8(ns); dn[1] = pack8(ns + 8);
    } else {
        int t = rr >> 4, q = rr & 15;
        unsigned short* p1 = bint + (size_t)t * TILE_USH + q * 32;  // [hi|lo]
        unsigned short* p2 = p1 + 512;                              // [hi|ns]
        uint4* d1 = (uint4*)p1;
        d1[0] = pack8(hs); d1[1] = pack8(hs + 8);
        d1[2] = pack8(ls); d1[3] = pack8(ls + 8);
        uint4* d2 = (uint4*)p2;
        d2[0] = pack8(hs); d2[1] = pack8(hs + 8);
        d2[2] = pack8(ns); d2[3] = pack8(ns + 8);
    }
}

// ---------------------------------------------------------------------------
// main: wave owns TWO 16x16 C tiles (32 eval cols) x one chunk (256 base rows).
// 4 waves/block share the chunk -> L1 reuse. A is register double-buffered.
__global__ __launch_bounds__(256, 8) void kde_mfma(
        const unsigned short* __restrict__ eh, const unsigned short* __restrict__ el,
        const unsigned short* __restrict__ en,
        const unsigned short* __restrict__ bint,
        float* __restrict__ part) {
    const int lane = threadIdx.x & 63;
    const int widx = threadIdx.x >> 6;
    const int b = blockIdx.x;                 // 0..4095
    const int chunk = b >> 6;                 // 0..63 (block-uniform)
    const int etp = (b & 63) * 4 + widx;      // 0..255 -> 32 eval cols
    const int cl = lane & 15;
    const int kg = lane >> 4;                 // 0..3 (k-slice)

    // B fragments (eval), resident for whole kernel.
    // B1 = [Bh|Bh]; B2 = [Bl|Bn] (kg<2 from el, else en).
    const size_t c0i = ((size_t)etp * 32 + cl) * 16;
    const size_t c1i = c0i + 16 * 16;
    const int kgo = (kg & 1) * 8;
    const bf16x8 B1_0 = *(const bf16x8*)(eh + c0i + kgo);
    const bf16x8 B1_1 = *(const bf16x8*)(eh + c1i + kgo);
    const unsigned short* b2src = (kg < 2) ? el : en;
    const bf16x8 B2_0 = *(const bf16x8*)(b2src + c0i + kgo);
    const bf16x8 B2_1 = *(const bf16x8*)(b2src + c1i + kgo);

    // A: one vaddr; plane1 at +0, plane2 at +512 ushorts (imm offset)
    const unsigned short* pa =
        bint + (size_t)chunk * CHUNK_USH + (size_t)cl * 32 + (size_t)kg * 8;

    float acc0 = 0.f, acc1 = 0.f, acc2 = 0.f, acc3 = 0.f;

    // prologue: load tile 0
    bf16x8 A1 = *(const bf16x8*)(pa);
    bf16x8 A2 = *(const bf16x8*)(pa + 512);

#pragma unroll 1
    for (int t = 0; t < TPC - 1; ++t) {
        // issue next tile's loads FIRST (oldest-outstanding = current tile)
        pa += TILE_USH;
        const bf16x8 A1n = *(const bf16x8*)(pa);
        const bf16x8 A2n = *(const bf16x8*)(pa + 512);

        f32x4 C0 = {0.f, 0.f, 0.f, 0.f};
        C0 = __builtin_amdgcn_mfma_f32_16x16x32_bf16(A1, B1_0, C0, 0, 0, 0);
        C0 = __builtin_amdgcn_mfma_f32_16x16x32_bf16(A2, B2_0, C0, 0, 0, 0);
        f32x4 C1 = {0.f, 0.f, 0.f, 0.f};
        C1 = __builtin_amdgcn_mfma_f32_16x16x32_bf16(A1, B1_1, C1, 0, 0, 0);
        C1 = __builtin_amdgcn_mfma_f32_16x16x32_bf16(A2, B2_1, C1, 0, 0, 0);

        acc0 += __builtin_amdgcn_exp2f(C0[0]);
        acc1 += __builtin_amdgcn_exp2f(C0[1]);
        acc2 += __builtin_amdgcn_exp2f(C0[2]);
        acc3 += __builtin_amdgcn_exp2f(C0[3]);
        acc0 += __builtin_amdgcn_exp2f(C1[0]);
        acc1 += __builtin_amdgcn_exp2f(C1[1]);
        acc2 += __builtin_amdgcn_exp2f(C1[2]);
        acc3 += __builtin_amdgcn_exp2f(C1[3]);

        A1 = A1n;
        A2 = A2n;
    }

    // peeled last tile
    {
        f32x4 C0 = {0.f, 0.f, 0.f, 0.f};
        C0 = __builtin_amdgcn_mfma_f32_16x16x32_bf16(A1, B1_0, C0, 0, 0, 0);
        C0 = __builtin_amdgcn_mfma_f32_16x16x32_bf16(A2, B2_0, C0, 0, 0, 0);
        f32x4 C1 = {0.f, 0.f, 0.f, 0.f};
        C1 = __builtin_amdgcn_mfma_f32_16x16x32_bf16(A1, B1_1, C1, 0, 0, 0);
        C1 = __builtin_amdgcn_mfma_f32_16x16x32_bf16(A2, B2_1, C1, 0, 0, 0);
        acc0 += __builtin_amdgcn_exp2f(C0[0]);
        acc1 += __builtin_amdgcn_exp2f(C0[1]);
        acc2 += __builtin_amdgcn_exp2f(C0[2]);
        acc3 += __builtin_amdgcn_exp2f(C0[3]);
        acc0 += __builtin_amdgcn_exp2f(C1[0]);
        acc1 += __builtin_amdgcn_exp2f(C1[1]);
        acc2 += __builtin_amdgcn_exp2f(C1[2]);
        acc3 += __builtin_amdgcn_exp2f(C1[3]);
    }

    // NOTE: acc layout — C0 rows go to eval cols [0,16), C1 to [16,32);
    // row-groups (base rows) fold across kg lanes.
    float s0 = acc0 + acc1 + acc2 + acc3;     // per-lane partial (4 C-rows)
    // Wait: C0/C1 share acc chains; recover per-tile sums via the fact that
    // both tiles' contributions belong to DIFFERENT output columns but the
    // same lane -- so we must NOT have merged them. (They were merged above;
    // see store below which handles the merged form.)
    // s0 currently = sum over both tiles' 4 rows for this lane.
    // Fold over kg (4 row-groups of the same 16 output cols per tile):
    // lanes with equal cl but different kg hold different base rows of BOTH
    // tiles -> fold across kg gives per-col sums of (tile0+tile1) -- WRONG.
    // Therefore: keep tiles separate. (Handled by using two lane-folds on the
    // un-merged quantities below.)
    (void)s0;

    float t0 = acc0 + acc1 + acc2 + acc3;     // placeholder, see below
    (void)t0;

    // Correct reduction: recompute per-tile sums. Since acc chains merged the
    // two tiles, redo: the merge is fine only if we store tile sums together.
    // To stay correct we re-split: impossible after merge -- so instead store
    // the merged value to BOTH? No. => Use separate accumulators per tile.
    part[0] = 0.f; // never executed path guard (see static_assert below)
}

// The above reduction concern is resolved by using per-tile accumulators;
// kde_mfma2 is the actual kernel used.
__global__ __launch_bounds__(256, 8) void kde_mfma2(
        const unsigned short* __restrict__ eh, const unsigned short* __restrict__ el,
        const unsigned short* __restrict__ en,
        const unsigned short* __restrict__ bint,
        float* __restrict__ part) {
    const int lane = threadIdx.x & 63;
    const int widx = threadIdx.x >> 6;
    const int b = blockIdx.x;
    const int chunk = b >> 6;
    const int etp = (b & 63) * 4 + widx;
    const int cl = lane & 15;
    const int kg = lane >> 4;

    const size_t c0i = ((size_t)etp * 32 + cl) * 16;
    const size_t c1i = c0i + 16 * 16;
    const int kgo = (kg & 1) * 8;
    const bf16x8 B1_0 = *(const bf16x8*)(eh + c0i + kgo);
    const bf16x8 B1_1 = *(const bf16x8*)(eh + c1i + kgo);
    const unsigned short* b2src = (kg < 2) ? el : en;
    const bf16x8 B2_0 = *(const bf16x8*)(b2src + c0i + kgo);
    const bf16x8 B2_1 = *(const bf16x8*)(b2src + c1i + kgo);

    const unsigned short* pa =
        bint + (size_t)chunk * CHUNK_USH + (size_t)cl * 32 + (size_t)kg * 8;

    float p0 = 0.f, p1 = 0.f, q0 = 0.f, q1 = 0.f;   // tile0/tile1, 2 chains each

    bf16x8 A1 = *(const bf16x8*)(pa);
    bf16x8 A2 = *(const bf16x8*)(pa + 512);

#pragma unroll 1
    for (int t = 0; t < TPC - 1; ++t) {
        pa += TILE_USH;
        const bf16x8 A1n = *(const bf16x8*)(pa);
        const bf16x8 A2n = *(const bf16x8*)(pa + 512);

        f32x4 C0 = {0.f, 0.f, 0.f, 0.f};
        C0 = __builtin_amdgcn_mfma_f32_16x16x32_bf16(A1, B1_0, C0, 0, 0, 0);
        C0 = __builtin_amdgcn_mfma_f32_16x16x32_bf16(A2, B2_0, C0, 0, 0, 0);
        f32x4 C1 = {0.f, 0.f, 0.f, 0.f};
        C1 = __builtin_amdgcn_mfma_f32_16x16x32_bf16(A1, B1_1, C1, 0, 0, 0);
        C1 = __builtin_amdgcn_mfma_f32_16x16x32_bf16(A2, B2_1, C1, 0, 0, 0);

        p0 += __builtin_amdgcn_exp2f(C0[0]);
        p1 += __builtin_amdgcn_exp2f(C0[1]);
        p0 += __builtin_amdgcn_exp2f(C0[2]);
        p1 += __builtin_amdgcn_exp2f(C0[3]);
        q0 += __builtin_amdgcn_exp2f(C1[0]);
        q1 += __builtin_amdgcn_exp2f(C1[1]);
        q0 += __builtin_amdgcn_exp2f(C1[2]);
        q1 += __builtin_amdgcn_exp2f(C1[3]);

        A1 = A1n;
        A2 = A2n;
    }
    {
        f32x4 C0 = {0.f, 0.f, 0.f, 0.f};
        C0 = __builtin_amdgcn_mfma_f32_16x16x32_bf16(A1, B1_0, C0, 0, 0, 0);
        C0 = __builtin_amdgcn_mfma_f32_16x16x32_bf16(A2, B2_0, C0, 0, 0, 0);
        f32x4 C1 = {0.f, 0.f, 0.f, 0.f};
        C1 = __builtin_amdgcn_mfma_f32_16x16x32_bf16(A1, B1_1, C1, 0, 0, 0);
        C1 = __builtin_amdgcn_mfma_f32_16x16x32_bf16(A2, B2_1, C1, 0, 0, 0);
        p0 += __builtin_amdgcn_exp2f(C0[0]);
        p1 += __builtin_amdgcn_exp2f(C0[1]);
        p0 += __builtin_amdgcn_exp2f(C0[2]);
        p1 += __builtin_amdgcn_exp2f(C0[3]);
        q0 += __builtin_amdgcn_exp2f(C1[0]);
        q1 += __builtin_amdgcn_exp2f(C1[1]);
        q0 += __builtin_amdgcn_exp2f(C1[2]);
        q1 += __builtin_amdgcn_exp2f(C1[3]);
    }

    float s0 = p0 + p1;                       // tile0: eval cols [0,16)
    float s1 = q0 + q1;                       // tile1: eval cols [16,32)
    s0 += __shfl_xor(s0, 16, 64);             // fold 4 kg row-groups
    s0 += __shfl_xor(s0, 32, 64);
    s1 += __shfl_xor(s1, 16, 64);
    s1 += __shfl_xor(s1, 32, 64);
    if (lane < 16) {
        float* p = part + (size_t)chunk * M_PTS + (size_t)etp * 32;
        p[cl]      = s0;
        p[16 + cl] = s1;
    }
}

// ---------------------------------------------------------------------------
__global__ __launch_bounds__(256) void kde_reduce(
        const float* __restrict__ part, const float* __restrict__ log_bw,
        float* __restrict__ out) {
    int m = blockIdx.x * 256 + threadIdx.x;
    if (m >= M_PTS) return;
    float lb = log_bw[0];
    float scale = __expf(-8.f * LOG_2PI_F - lb) / (float)N_PTS;
    float s = 0.f;
#pragma unroll
    for (int c = 0; c < NCH; ++c) s += part[(size_t)c * M_PTS + m];
    out[m] = scale * s;
}

// ---------------------------------------------------------------------------
extern "C" void kernel_launch(void* const* d_in, const int* in_sizes, int n_in,
                              void* d_out, int out_size, void* d_ws, size_t ws_size,
                              hipStream_t stream) {
    const float* xe = (const float*)d_in[0];   // [8192,16]
    const float* xb = (const float*)d_in[1];   // [16384,16]
    const float* lb = (const float*)d_in[2];   // [1]
    float* out = (float*)d_out;                // [8192]

    unsigned short* bint = (unsigned short*)d_ws;            // 1024 tiles * 1024 ush
    unsigned short* eh = bint + (size_t)(N_PTS / 16) * TILE_USH;
    unsigned short* el = eh + (size_t)M_PTS * 16;
    unsigned short* en = el + (size_t)M_PTS * 16;
    float* part = (float*)(en + (size_t)M_PTS * 16);         // NCH*M_PTS floats

    kde_pack<<<(N_PTS + M_PTS) / 256, 256, 0, stream>>>(xe, xb, lb,
                                                        bint, eh, el, en);
    kde_mfma2<<<4096, 256, 0, stream>>>(eh, el, en, bint, part);
    kde_reduce<<<M_PTS / 256, 256, 0, stream>>>(part, lb, out);
}